// Round 7
// baseline (306.239 us; speedup 1.0000x reference)
//
#include <hip/hip_runtime.h>
#include <hip/hip_bf16.h>

// QuantizedLinear: out[M,O] = x[M,K] @ W[O,K]^T + bias, W 4-bit group-quant (G=64)
// M=8192, O=4096, K=4096.
// Round 7: round-6 structure (8-phase 256x256, XCD swizzle) with ONE change:
// MFMA 16x16x32 -> 32x32x16 (pipe floor 620->516 cyc/phase, half the MFMA instrs).
// Schedule, staging, vmcnt algebra, LDS layout all byte-identical to round 6.

typedef short short8 __attribute__((ext_vector_type(8)));
typedef float float4v __attribute__((ext_vector_type(4)));
typedef float f32x16 __attribute__((ext_vector_type(16)));
typedef int int4v __attribute__((ext_vector_type(4)));

#define M_TOTAL 8192
#define N_OUT 4096
#define K_IN 4096
#define BM 256
#define BN 256
#define BK 64
#define NT (K_IN / BK) // 64 K-tiles

// RTNE float->bf16
__device__ __forceinline__ short f2bf(float f) {
  unsigned int u = __builtin_bit_cast(unsigned int, f);
  unsigned int r = (u + 0x7fffu + ((u >> 16) & 1u)) >> 16;
  return (short)(unsigned short)r;
}

__device__ __forceinline__ void gload_lds16(const void* g, void* l) {
  __builtin_amdgcn_global_load_lds(
      (const __attribute__((address_space(1))) void*)g,
      (__attribute__((address_space(3))) void*)l, 16, 0, 0);
}

// ---------------- prepass 1: x f32 -> bf16 ----------------
__global__ __launch_bounds__(256)
void cvt_x_kernel(const float* __restrict__ x, short* __restrict__ xb, int n8) {
  int i = blockIdx.x * blockDim.x + threadIdx.x;
  int stride = gridDim.x * blockDim.x;
  for (; i < n8; i += stride) {
    const float* p = x + (size_t)i * 8;
    float4v f0 = *reinterpret_cast<const float4v*>(p);
    float4v f1 = *reinterpret_cast<const float4v*>(p + 4);
    short8 v;
#pragma unroll
    for (int e = 0; e < 4; ++e) { v[e] = f2bf(f0[e]); v[4 + e] = f2bf(f1[e]); }
    *reinterpret_cast<short8*>(xb + (size_t)i * 8) = v;
  }
}

// ---------------- prepass 2: W 4-bit -> bf16 [O][K] ----------------
__global__ __launch_bounds__(256)
void deq_w_kernel(const int* __restrict__ wp, const float* __restrict__ wsc,
                  const float* __restrict__ wzr, short* __restrict__ wb) {
  int t = blockIdx.x * blockDim.x + threadIdx.x; // 0..524287
  int g = t >> 1, h = t & 1;
  float s = wsc[g], z = wzr[g];
  const int* p = wp + (size_t)g * 32 + h * 16;
  int4v b[4];
#pragma unroll
  for (int u = 0; u < 4; ++u) b[u] = *reinterpret_cast<const int4v*>(p + u * 4);
  short* o = wb + (size_t)t * 32;
#pragma unroll
  for (int u = 0; u < 4; ++u) {
    short8 v;
#pragma unroll
    for (int e = 0; e < 4; ++e) {
      int bb = b[u][e];
      v[2 * e]     = f2bf((float)(bb & 15) * s + z);
      v[2 * e + 1] = f2bf((float)((bb >> 4) & 15) * s + z);
    }
    *reinterpret_cast<short8*>(o + u * 8) = v;
  }
}

// ---------------- main GEMM: 256x256 tile, 8-phase, 8 waves, MFMA 32x32x16 ----------------
#define MFMA32 __builtin_amdgcn_mfma_f32_32x32x16_bf16
#define BAR() __builtin_amdgcn_s_barrier()
#define PRIO1() __builtin_amdgcn_s_setprio(1)
#define PRIO0() __builtin_amdgcn_s_setprio(0)
#define VMCNT6() asm volatile("s_waitcnt vmcnt(6)" ::: "memory")
#define VMCNT0() asm volatile("s_waitcnt vmcnt(0)" ::: "memory")

#define ZERO16 {0.f,0.f,0.f,0.f,0.f,0.f,0.f,0.f,0.f,0.f,0.f,0.f,0.f,0.f,0.f,0.f}

__global__ __launch_bounds__(512, 2)
void qgemm8_kernel(const short* __restrict__ A, const short* __restrict__ B,
                   const float* __restrict__ bias, float* __restrict__ out) {
  __shared__ __align__(16) char L[131072];

  const int tid  = threadIdx.x;
  const int lane = tid & 63;
  const int w    = tid >> 6;  // 0..7
  const int wm   = w >> 2;    // 0..1  (M half)
  const int wn   = w & 3;     // 0..3  (N quarter)

  // XCD-chunked swizzle over 512 blocks (2 dispatch rounds of 256).
  const int id  = blockIdx.x;
  const int xcd = id & 7;
  const int s   = id >> 3;   // 0..63
  const int by  = (s >> 5) * 16 + 2 * xcd + ((s & 31) >> 4);
  const int bx  = s & 15;
  const int m0  = by * BM;
  const int o0  = bx * BN;

  // ---- staging precompute (identical to round 6) ----
  const int kslot = (lane & 7) ^ ((lane >> 3) & 7);     // pre-swizzled global k-slot
  const int R0 = w * 16 + (lane >> 3);                  // piece row q=0 (0..127)
  const int R1 = R0 + 8;                                // piece row q=1
  const short* pA0 = A + (size_t)(m0 + (R0 >> 6) * 128 + (R0 & 63)) * K_IN + kslot * 8;
  const short* pA1 = A + (size_t)(m0 + (R1 >> 6) * 128 + (R1 & 63)) * K_IN + kslot * 8;
  const short* pB0 = B + (size_t)(o0 + (R0 >> 5) * 64 + (R0 & 31)) * K_IN + kslot * 8;
  const short* pB1 = B + (size_t)(o0 + (R1 >> 5) * 64 + (R1 & 31)) * K_IN + kslot * 8;
  const int ldsp0 = w * 2048 + lane * 16;               // linear LDS piece dest (bytes)
  const int ldsp1 = ldsp0 + 1024;

#define STAGE_A(buf, mg, t) do { \
    gload_lds16(pA0 + (size_t)(mg) * 64 * K_IN + (t) * 64, &L[(buf) * 65536 + (mg) * 16384 + ldsp0]); \
    gload_lds16(pA1 + (size_t)(mg) * 64 * K_IN + (t) * 64, &L[(buf) * 65536 + (mg) * 16384 + ldsp1]); \
  } while (0)
#define STAGE_B(buf, ng, t) do { \
    gload_lds16(pB0 + (size_t)(ng) * 32 * K_IN + (t) * 64, &L[(buf) * 65536 + 32768 + (ng) * 16384 + ldsp0]); \
    gload_lds16(pB1 + (size_t)(ng) * 32 * K_IN + (t) * 64, &L[(buf) * 65536 + 32768 + (ng) * 16384 + ldsp1]); \
  } while (0)

  // ---- fragment-read precompute (32x32x16 layout) ----
  // A-frag: lane holds row (lane&31), k = (lane>>5)*8 + e. Same map for B (cols).
  const int l31 = lane & 31;
  const int hi  = lane >> 5;
  const int lo7 = lane & 7;
  int sl[4];
#pragma unroll
  for (int ks = 0; ks < 4; ++ks) sl[ks] = (((ks * 2) + hi) ^ lo7) << 4; // swizzled 16B slot

  const int arow = wm * 8192 + l31 * 128;          // within A region [wh=wm][64r][128B]
  const int brow = 32768 + wn * 4096 + l31 * 128;  // within B region [128r][128B]

  short8 a[8], bl[4], br[4];

  // a[mt2*4+ks]: M-tile mt2 (32 rows), K-step ks (16 k)
#define RD_A(buf, mg) do { \
    _Pragma("unroll") for (int mt2 = 0; mt2 < 2; ++mt2) { \
      const int base2 = (buf) * 65536 + (mg) * 16384 + arow + mt2 * 4096; \
      _Pragma("unroll") for (int ks = 0; ks < 4; ++ks) \
        a[mt2 * 4 + ks] = *reinterpret_cast<const short8*>(&L[base2 + sl[ks]]); \
    } } while (0)
#define RD_B(dst, buf, ng) do { \
    const int base2 = (buf) * 65536 + (ng) * 16384 + brow; \
    _Pragma("unroll") for (int ks = 0; ks < 4; ++ks) \
      dst[ks] = *reinterpret_cast<const short8*>(&L[base2 + sl[ks]]); \
  } while (0)

  f32x16 acc[4][2]; // [mg*2+mt2][ng]
#pragma unroll
  for (int i = 0; i < 4; ++i)
#pragma unroll
    for (int j = 0; j < 2; ++j) acc[i][j] = (f32x16)ZERO16;

  // quad (mg,ng): 2 M-tiles x 1 N-tile x 4 K-steps = 8 MFMA 32x32x16
#define DO_QUAD(mg, ng, bb_) do { \
    _Pragma("unroll") for (int ks = 0; ks < 4; ++ks) \
    _Pragma("unroll") for (int mt2 = 0; mt2 < 2; ++mt2) \
      acc[(mg) * 2 + mt2][(ng)] = \
        MFMA32(a[mt2 * 4 + ks], bb_[ks], acc[(mg) * 2 + mt2][(ng)], 0, 0, 0); \
  } while (0)

  // ---- prologue: kt0 (4 chunks, buf0) + kt1 (3 chunks, buf1) ----
  STAGE_A(0, 0, 0); STAGE_B(0, 1, 0); STAGE_B(0, 0, 0); STAGE_A(0, 1, 0);
  STAGE_A(1, 0, 1); STAGE_B(1, 1, 1); STAGE_B(1, 0, 1);
  VMCNT6();  // oldest 4 chunks (= all of kt0) landed
  BAR();

  // ---- main loop: iterations 0..30 compute kt=2i (buf0), kt+1 (buf1) ----
  for (int i = 0; i < NT / 2 - 1; ++i) {
    const int t2 = 2 * i + 2, t3 = 2 * i + 3;
    // ph1: Q1(kt) | stage kt+1.Abot -> buf1
    RD_A(0, 0); RD_B(br, 0, 1);
    STAGE_A(1, 1, t3 - 2);
    BAR(); PRIO1(); DO_QUAD(0, 1, br); PRIO0(); BAR();
    // ph2: Q2(kt) | stage kt+2.Atop -> buf0
    RD_B(bl, 0, 0);
    STAGE_A(0, 0, t2);
    BAR(); PRIO1(); DO_QUAD(0, 0, bl); PRIO0(); BAR();
    // ph3: Q3(kt) | stage kt+2.Bright -> buf0
    RD_A(0, 1);
    STAGE_B(0, 1, t2);
    BAR(); PRIO1(); DO_QUAD(1, 0, bl); PRIO0(); BAR();
    // ph4: Q4(kt, br reused) | stage kt+2.Bleft -> buf0 | vmcnt(6)
    STAGE_B(0, 0, t2);
    VMCNT6();  // guarantees kt+1 fully landed
    BAR(); PRIO1(); DO_QUAD(1, 1, br); PRIO0(); BAR();
    // ph5: Q1(kt+1) | stage kt+2.Abot -> buf0
    RD_A(1, 0); RD_B(br, 1, 1);
    STAGE_A(0, 1, t2);
    BAR(); PRIO1(); DO_QUAD(0, 1, br); PRIO0(); BAR();
    // ph6: Q2(kt+1) | stage kt+3.Atop -> buf1
    RD_B(bl, 1, 0);
    STAGE_A(1, 0, t3);
    BAR(); PRIO1(); DO_QUAD(0, 0, bl); PRIO0(); BAR();
    // ph7: Q3(kt+1) | stage kt+3.Bright -> buf1
    RD_A(1, 1);
    STAGE_B(1, 1, t3);
    BAR(); PRIO1(); DO_QUAD(1, 0, bl); PRIO0(); BAR();
    // ph8: Q4(kt+1) | stage kt+3.Bleft -> buf1 | vmcnt(6)
    STAGE_B(1, 0, t3);
    VMCNT6();  // guarantees kt+2 fully landed
    BAR(); PRIO1(); DO_QUAD(1, 1, br); PRIO0(); BAR();
  }

  // ---- epilogue: kt=62 (buf0), kt=63 (buf1) ----
  RD_A(0, 0); RD_B(br, 0, 1);
  STAGE_A(1, 1, 63);  // kt63.Abot
  BAR(); PRIO1(); DO_QUAD(0, 1, br); PRIO0(); BAR();
  RD_B(bl, 0, 0);
  BAR(); PRIO1(); DO_QUAD(0, 0, bl); PRIO0(); BAR();
  RD_A(0, 1);
  BAR(); PRIO1(); DO_QUAD(1, 0, bl); PRIO0(); BAR();
  VMCNT0();  // drain: kt63 fully landed
  BAR(); PRIO1(); DO_QUAD(1, 1, br); PRIO0(); BAR();
  RD_A(1, 0); RD_B(br, 1, 1);
  BAR(); PRIO1(); DO_QUAD(0, 1, br); PRIO0(); BAR();
  RD_B(bl, 1, 0);
  BAR(); PRIO1(); DO_QUAD(0, 0, bl); PRIO0(); BAR();
  RD_A(1, 1);
  BAR(); PRIO1(); DO_QUAD(1, 0, bl); PRIO0(); BAR();
  PRIO1(); DO_QUAD(1, 1, br); PRIO0();

  // ---- C write: 32x32 C/D layout (verified m74/m101):
  // col = lane&31, row = (reg&3) + 8*(reg>>2) + 4*(lane>>5)
#pragma unroll
  for (int ng = 0; ng < 2; ++ng) {
    const int col = o0 + wn * 64 + ng * 32 + l31;
    const float bb = bias[col];
#pragma unroll
    for (int ai = 0; ai < 4; ++ai) {
      const int rowb = m0 + wm * 128 + (ai >> 1) * 64 + (ai & 1) * 32 + hi * 4;
#pragma unroll
      for (int rq = 0; rq < 4; ++rq)
#pragma unroll
        for (int r2 = 0; r2 < 4; ++r2)
          out[(size_t)(rowb + rq * 8 + r2) * N_OUT + col] = acc[ai][ng][rq * 4 + r2] + bb;
    }
  }
}

extern "C" void kernel_launch(void* const* d_in, const int* in_sizes, int n_in,
                              void* d_out, int out_size, void* d_ws, size_t ws_size,
                              hipStream_t stream) {
  const float* x    = (const float*)d_in[0];
  const int* wp     = (const int*)d_in[1];
  const float* wsc  = (const float*)d_in[2];
  const float* wzr  = (const float*)d_in[3];
  const float* bias = (const float*)d_in[4];
  float* out = (float*)d_out;

  const size_t xb_bytes = (size_t)M_TOTAL * K_IN * 2;
  short* xb = (short*)d_ws;
  short* wb = (short*)((char*)d_ws + xb_bytes);

  cvt_x_kernel<<<2048, 256, 0, stream>>>(x, xb, (int)((size_t)M_TOTAL * K_IN / 8));
  deq_w_kernel<<<2048, 256, 0, stream>>>(wp, wsc, wzr, wb);
  qgemm8_kernel<<<dim3(512), dim3(512), 0, stream>>>(xb, wb, bias, out);
}

// Round 8
// 269.771 us; speedup vs baseline: 1.1352x; 1.1352x over previous
//
#include <hip/hip_runtime.h>
#include <hip/hip_bf16.h>

// QuantizedLinear: out[M,O] = x[M,K] @ W[O,K]^T + bias, W 4-bit group-quant (G=64)
// M=8192, O=4096, K=4096.
// Round 8: round-6 kernel (16x16x32, 8-phase, 0-conflict swizzle, XCD swizzle) with ONE
// structural change: SINGLE barrier per phase (drop pre-MFMA barrier). Phase order:
// {RD; STAGE; MFMA(lgkm); [vmcnt]; BAR}. Reads are consumed before each phase's barrier,
// so barrier(p-1) ordering still guarantees STAGE(p) never overwrites live data.
// Round 7's 32x32 MFMA reverted: 32-row reads + 8-slot swizzle = structural 4-way
// bank conflict (2.5e7 measured), MfmaUtil 51->45.

typedef short short8 __attribute__((ext_vector_type(8)));
typedef float float4v __attribute__((ext_vector_type(4)));
typedef int int4v __attribute__((ext_vector_type(4)));

#define M_TOTAL 8192
#define N_OUT 4096
#define K_IN 4096
#define BM 256
#define BN 256
#define BK 64
#define NT (K_IN / BK) // 64 K-tiles

// RTNE float->bf16
__device__ __forceinline__ short f2bf(float f) {
  unsigned int u = __builtin_bit_cast(unsigned int, f);
  unsigned int r = (u + 0x7fffu + ((u >> 16) & 1u)) >> 16;
  return (short)(unsigned short)r;
}

__device__ __forceinline__ void gload_lds16(const void* g, void* l) {
  __builtin_amdgcn_global_load_lds(
      (const __attribute__((address_space(1))) void*)g,
      (__attribute__((address_space(3))) void*)l, 16, 0, 0);
}

// ---------------- prepass 1: x f32 -> bf16 ----------------
__global__ __launch_bounds__(256)
void cvt_x_kernel(const float* __restrict__ x, short* __restrict__ xb, int n8) {
  int i = blockIdx.x * blockDim.x + threadIdx.x;
  int stride = gridDim.x * blockDim.x;
  for (; i < n8; i += stride) {
    const float* p = x + (size_t)i * 8;
    float4v f0 = *reinterpret_cast<const float4v*>(p);
    float4v f1 = *reinterpret_cast<const float4v*>(p + 4);
    short8 v;
#pragma unroll
    for (int e = 0; e < 4; ++e) { v[e] = f2bf(f0[e]); v[4 + e] = f2bf(f1[e]); }
    *reinterpret_cast<short8*>(xb + (size_t)i * 8) = v;
  }
}

// ---------------- prepass 2: W 4-bit -> bf16 [O][K] ----------------
__global__ __launch_bounds__(256)
void deq_w_kernel(const int* __restrict__ wp, const float* __restrict__ wsc,
                  const float* __restrict__ wzr, short* __restrict__ wb) {
  int t = blockIdx.x * blockDim.x + threadIdx.x; // 0..524287
  int g = t >> 1, h = t & 1;
  float s = wsc[g], z = wzr[g];
  const int* p = wp + (size_t)g * 32 + h * 16;
  int4v b[4];
#pragma unroll
  for (int u = 0; u < 4; ++u) b[u] = *reinterpret_cast<const int4v*>(p + u * 4);
  short* o = wb + (size_t)t * 32;
#pragma unroll
  for (int u = 0; u < 4; ++u) {
    short8 v;
#pragma unroll
    for (int e = 0; e < 4; ++e) {
      int bb = b[u][e];
      v[2 * e]     = f2bf((float)(bb & 15) * s + z);
      v[2 * e + 1] = f2bf((float)((bb >> 4) & 15) * s + z);
    }
    *reinterpret_cast<short8*>(o + u * 8) = v;
  }
}

// ---------------- main GEMM: 256x256 tile, 8-phase single-barrier, 8 waves ----------------
#define MFMA_BF16 __builtin_amdgcn_mfma_f32_16x16x32_bf16
#define BAR() __builtin_amdgcn_s_barrier()
#define PRIO1() __builtin_amdgcn_s_setprio(1)
#define PRIO0() __builtin_amdgcn_s_setprio(0)
#define VMCNT6() asm volatile("s_waitcnt vmcnt(6)" ::: "memory")
#define VMCNT0() asm volatile("s_waitcnt vmcnt(0)" ::: "memory")

__global__ __launch_bounds__(512, 2)
void qgemm8_kernel(const short* __restrict__ A, const short* __restrict__ B,
                   const float* __restrict__ bias, float* __restrict__ out) {
  __shared__ __align__(16) char L[131072];

  const int tid  = threadIdx.x;
  const int lane = tid & 63;
  const int w    = tid >> 6;  // 0..7
  const int wm   = w >> 2;    // 0..1  (M half)
  const int wn   = w & 3;     // 0..3  (N quarter)

  // XCD-chunked swizzle over 512 blocks (2 dispatch rounds of 256).
  const int id  = blockIdx.x;
  const int xcd = id & 7;
  const int s   = id >> 3;   // 0..63
  const int by  = (s >> 5) * 16 + 2 * xcd + ((s & 31) >> 4);
  const int bx  = s & 15;
  const int m0  = by * BM;
  const int o0  = bx * BN;

  // ---- staging precompute (per thread) ----
  const int kslot = (lane & 7) ^ ((lane >> 3) & 7);     // pre-swizzled global k-slot
  const int R0 = w * 16 + (lane >> 3);                  // piece row q=0 (0..127)
  const int R1 = R0 + 8;                                // piece row q=1
  const short* pA0 = A + (size_t)(m0 + (R0 >> 6) * 128 + (R0 & 63)) * K_IN + kslot * 8;
  const short* pA1 = A + (size_t)(m0 + (R1 >> 6) * 128 + (R1 & 63)) * K_IN + kslot * 8;
  const short* pB0 = B + (size_t)(o0 + (R0 >> 5) * 64 + (R0 & 31)) * K_IN + kslot * 8;
  const short* pB1 = B + (size_t)(o0 + (R1 >> 5) * 64 + (R1 & 31)) * K_IN + kslot * 8;
  const int ldsp0 = w * 2048 + lane * 16;               // linear LDS piece dest (bytes)
  const int ldsp1 = ldsp0 + 1024;

#define STAGE_A(buf, mg, t) do { \
    gload_lds16(pA0 + (size_t)(mg) * 64 * K_IN + (t) * 64, &L[(buf) * 65536 + (mg) * 16384 + ldsp0]); \
    gload_lds16(pA1 + (size_t)(mg) * 64 * K_IN + (t) * 64, &L[(buf) * 65536 + (mg) * 16384 + ldsp1]); \
  } while (0)
#define STAGE_B(buf, ng, t) do { \
    gload_lds16(pB0 + (size_t)(ng) * 32 * K_IN + (t) * 64, &L[(buf) * 65536 + 32768 + (ng) * 16384 + ldsp0]); \
    gload_lds16(pB1 + (size_t)(ng) * 32 * K_IN + (t) * 64, &L[(buf) * 65536 + 32768 + (ng) * 16384 + ldsp1]); \
  } while (0)

  // ---- fragment-read precompute ----
  const int l15   = lane & 15;
  const int abase = wm * 8192 + l15 * 128;          // within A region [wh][64r][128B]
  const int bbase = 32768 + wn * 4096 + l15 * 128;  // within B region [128r][128B]
  const int sl0 = (((lane >> 4) + 0) ^ (lane & 7)) * 16; // swizzled 16B slot, ks=0
  const int sl1 = (((lane >> 4) + 4) ^ (lane & 7)) * 16; // ks=1

  short8 a[8], bl[4], br[4];

#define RD_A(buf, mg) do { \
    _Pragma("unroll") for (int mf = 0; mf < 4; ++mf) { \
      a[mf * 2 + 0] = *reinterpret_cast<const short8*>(&L[(buf) * 65536 + (mg) * 16384 + abase + mf * 2048 + sl0]); \
      a[mf * 2 + 1] = *reinterpret_cast<const short8*>(&L[(buf) * 65536 + (mg) * 16384 + abase + mf * 2048 + sl1]); \
    } } while (0)
#define RD_B(dst, buf, ng) do { \
    _Pragma("unroll") for (int nf = 0; nf < 2; ++nf) { \
      dst[nf * 2 + 0] = *reinterpret_cast<const short8*>(&L[(buf) * 65536 + (ng) * 16384 + bbase + nf * 2048 + sl0]); \
      dst[nf * 2 + 1] = *reinterpret_cast<const short8*>(&L[(buf) * 65536 + (ng) * 16384 + bbase + nf * 2048 + sl1]); \
    } } while (0)

  float4v acc[8][4];
#pragma unroll
  for (int i = 0; i < 8; ++i)
#pragma unroll
    for (int j = 0; j < 4; ++j) acc[i][j] = (float4v){0.f, 0.f, 0.f, 0.f};

#define DO_QUAD(mg, ng, bb_) do { \
    _Pragma("unroll") for (int ks = 0; ks < 2; ++ks) \
    _Pragma("unroll") for (int mf = 0; mf < 4; ++mf) \
    _Pragma("unroll") for (int nf = 0; nf < 2; ++nf) \
      acc[(mg) * 4 + mf][(ng) * 2 + nf] = \
        MFMA_BF16(a[mf * 2 + ks], bb_[nf * 2 + ks], acc[(mg) * 4 + mf][(ng) * 2 + nf], 0, 0, 0); \
  } while (0)

  // ---- prologue: kt0 (4 chunks, buf0) + kt1 (3 chunks, buf1) ----
  STAGE_A(0, 0, 0); STAGE_B(0, 1, 0); STAGE_B(0, 0, 0); STAGE_A(0, 1, 0);
  STAGE_A(1, 0, 1); STAGE_B(1, 1, 1); STAGE_B(1, 0, 1);
  VMCNT6();  // oldest 4 chunks (= all of kt0) landed
  BAR();

  // ---- main loop: iterations 0..30 compute kt=2i (buf0), kt+1 (buf1) ----
  // Single barrier per phase: {RD; STAGE; MFMA; [vmcnt]; BAR}.
  for (int i = 0; i < NT / 2 - 1; ++i) {
    const int t2 = 2 * i + 2, t3 = 2 * i + 3;
    // ph1: Q1(kt) | stage kt+1.Abot -> buf1
    RD_A(0, 0); RD_B(br, 0, 1);
    STAGE_A(1, 1, t3 - 2);
    PRIO1(); DO_QUAD(0, 1, br); PRIO0(); BAR();
    // ph2: Q2(kt) | stage kt+2.Atop -> buf0 (last read ph1)
    RD_B(bl, 0, 0);
    STAGE_A(0, 0, t2);
    PRIO1(); DO_QUAD(0, 0, bl); PRIO0(); BAR();
    // ph3: Q3(kt) | stage kt+2.Bright -> buf0 (last read ph1)
    RD_A(0, 1);
    STAGE_B(0, 1, t2);
    PRIO1(); DO_QUAD(1, 0, bl); PRIO0(); BAR();
    // ph4: Q4(kt, br regs) | stage kt+2.Bleft -> buf0 (last read ph2) | vmcnt(6)
    STAGE_B(0, 0, t2);
    PRIO1(); DO_QUAD(1, 1, br); PRIO0();
    VMCNT6();  // kt+1 fully landed before ph5 reads buf1
    BAR();
    // ph5: Q1(kt+1) | stage kt+2.Abot -> buf0 (last read ph3)
    RD_A(1, 0); RD_B(br, 1, 1);
    STAGE_A(0, 1, t2);
    PRIO1(); DO_QUAD(0, 1, br); PRIO0(); BAR();
    // ph6: Q2(kt+1) | stage kt+3.Atop -> buf1 (last read ph5)
    RD_B(bl, 1, 0);
    STAGE_A(1, 0, t3);
    PRIO1(); DO_QUAD(0, 0, bl); PRIO0(); BAR();
    // ph7: Q3(kt+1) | stage kt+3.Bright -> buf1 (last read ph5)
    RD_A(1, 1);
    STAGE_B(1, 1, t3);
    PRIO1(); DO_QUAD(1, 0, bl); PRIO0(); BAR();
    // ph8: Q4(kt+1) | stage kt+3.Bleft -> buf1 (last read ph6) | vmcnt(6)
    STAGE_B(1, 0, t3);
    PRIO1(); DO_QUAD(1, 1, br); PRIO0();
    VMCNT6();  // kt+2 fully landed before next ph1 reads buf0
    BAR();
  }

  // ---- epilogue: kt=62 (buf0), kt=63 (buf1) ----
  RD_A(0, 0); RD_B(br, 0, 1);
  STAGE_A(1, 1, 63);  // kt63.Abot
  PRIO1(); DO_QUAD(0, 1, br); PRIO0(); BAR();
  RD_B(bl, 0, 0);
  PRIO1(); DO_QUAD(0, 0, bl); PRIO0(); BAR();
  RD_A(0, 1);
  PRIO1(); DO_QUAD(1, 0, bl); PRIO0();
  VMCNT0();  // kt63 fully landed before ph5' reads buf1
  BAR();
  PRIO1(); DO_QUAD(1, 1, br); PRIO0(); BAR();
  RD_A(1, 0); RD_B(br, 1, 1);
  PRIO1(); DO_QUAD(0, 1, br); PRIO0(); BAR();
  RD_B(bl, 1, 0);
  PRIO1(); DO_QUAD(0, 0, bl); PRIO0(); BAR();
  RD_A(1, 1);
  PRIO1(); DO_QUAD(1, 0, bl); PRIO0(); BAR();
  PRIO1(); DO_QUAD(1, 1, br); PRIO0();

  // ---- C write: col = o0 + wn*64 + nf*16 + (lane&15); row = m0 + wm*128 + mf*16 + (lane>>4)*4 + r
#pragma unroll
  for (int nf = 0; nf < 4; ++nf) {
    const int col = o0 + wn * 64 + nf * 16 + l15;
    const float bb = bias[col];
#pragma unroll
    for (int mf = 0; mf < 8; ++mf) {
      const int rowb = m0 + wm * 128 + mf * 16 + (lane >> 4) * 4;
#pragma unroll
      for (int r = 0; r < 4; ++r)
        out[(size_t)(rowb + r) * N_OUT + col] = acc[mf][nf][r] + bb;
    }
  }
}

extern "C" void kernel_launch(void* const* d_in, const int* in_sizes, int n_in,
                              void* d_out, int out_size, void* d_ws, size_t ws_size,
                              hipStream_t stream) {
  const float* x    = (const float*)d_in[0];
  const int* wp     = (const int*)d_in[1];
  const float* wsc  = (const float*)d_in[2];
  const float* wzr  = (const float*)d_in[3];
  const float* bias = (const float*)d_in[4];
  float* out = (float*)d_out;

  const size_t xb_bytes = (size_t)M_TOTAL * K_IN * 2;
  short* xb = (short*)d_ws;
  short* wb = (short*)((char*)d_ws + xb_bytes);

  cvt_x_kernel<<<2048, 256, 0, stream>>>(x, xb, (int)((size_t)M_TOTAL * K_IN / 8));
  deq_w_kernel<<<2048, 256, 0, stream>>>(wp, wsc, wzr, wb);
  qgemm8_kernel<<<dim3(512), dim3(512), 0, stream>>>(xb, wb, bias, out);
}